// Round 4
// baseline (212.887 us; speedup 1.0000x reference)
//
#include <hip/hip_runtime.h>
#include <hip/hip_fp16.h>
#include <cmath>

// SVC_63737314673237 round 4: conflict-free LDS split-f16 MFMA GEMM.
// Math identical to R2/R3 (verified absmax 0.0): dot = xh.sh + 2^-12*(xh.sl'+xl'.sh).
// R3 post-mortem: (kslot+row)&3 swizzle on 64B rows left 4-way bank conflicts
// (SQ_LDS_BANK_CONFLICT 7.86e6). Fix: 80B row stride + (ks+(row>>3))&3 swizzle
// -> exactly 8 words/bank/wave-instr on all frag reads and staging writes.
// Single-buffered tiles (dbuf was neutral), register prefetch, hoisted addrs.

#define GAMMA 0.01f
constexpr int N  = 8192;
constexpr int D  = 256;
constexpr int S  = 5000;
constexpr int C  = 10;
constexpr int NV = 500;
constexpr int R  = 9;   // C-1
constexpr int LW = 40;  // LDS row stride in f16 (80 B): conflict-free w/ swizzle

typedef _Float16 f16x8 __attribute__((ext_vector_type(8)));
typedef _Float16 f16x4 __attribute__((ext_vector_type(4)));
typedef float    f32x4 __attribute__((ext_vector_type(4)));

// ---------------- fused split + norms: one wave per row ---------------------
__global__ __launch_bounds__(256) void prep_kernel(const float* __restrict__ x,
                                                   const float* __restrict__ sv,
                                                   _Float16* __restrict__ xh,
                                                   _Float16* __restrict__ xl,
                                                   _Float16* __restrict__ sh,
                                                   _Float16* __restrict__ sl,
                                                   float* __restrict__ xn,
                                                   float* __restrict__ svn) {
    int gid  = blockIdx.x * blockDim.x + threadIdx.x;
    int wid  = gid >> 6;
    int lane = gid & 63;
    if (wid >= N + S) return;
    bool isx = wid < N;
    int  r   = isx ? wid : wid - N;
    const float* row = isx ? (x + (size_t)r * D) : (sv + (size_t)r * D);
    float4 v = reinterpret_cast<const float4*>(row)[lane];
    float s = v.x * v.x + v.y * v.y + v.z * v.z + v.w * v.w;
#pragma unroll
    for (int off = 32; off > 0; off >>= 1) s += __shfl_xor(s, off, 64);
    float vv[4] = {v.x, v.y, v.z, v.w};
    f16x4 h, l;
#pragma unroll
    for (int k = 0; k < 4; ++k) {
        _Float16 hi = (_Float16)vv[k];
        h[k] = hi;
        l[k] = (_Float16)((vv[k] - (float)hi) * 4096.0f);
    }
    size_t o = (size_t)r * D + lane * 4;
    *(f16x4*)((isx ? xh : sh) + o) = h;
    *(f16x4*)((isx ? xl : sl) + o) = l;
    if (lane == 0) (isx ? xn : svn)[r] = s;
}

// ---------------- split-MFMA GEMM + exp + weighted reduce -------------------
// grid (128 row tiles, 10 classes); 4 waves 2x2; wave tile 32x64 (2x4 of
// 16x16x32). 32 phases = 4 chunks x 8 kb, single-buffer LDS, reg prefetch.
__global__ __launch_bounds__(256, 2) void svc_gemm(const _Float16* __restrict__ xh,
                                                   const _Float16* __restrict__ xl,
                                                   const _Float16* __restrict__ sh,
                                                   const _Float16* __restrict__ sl,
                                                   const float* __restrict__ a,
                                                   const float* __restrict__ xnorm,
                                                   const float* __restrict__ svnorm,
                                                   float* __restrict__ T) {
    __shared__ _Float16 As[2][64 * LW];    // [plane][row*40 + swzslot*8]
    __shared__ _Float16 Bs[2][128 * LW];
    __shared__ float a_sh[R][512];
    __shared__ float sn_sh[512];
    __shared__ float tred[64 * R];

    const int tid  = threadIdx.x;
    const int n0   = blockIdx.x * 64;
    const int cls  = blockIdx.y;
    const int w    = tid >> 6;
    const int lane = tid & 63;
    const int wm   = w >> 1;
    const int wn   = w & 1;
    const int lx   = lane & 15;
    const int quad = lane >> 4;

    for (int i = tid; i < R * 512; i += 256) {
        int r = i >> 9, cseg = i & 511;
        a_sh[r][cseg] = (cseg < NV) ? a[(size_t)r * S + cls * NV + cseg] : 0.0f;
    }
    for (int i = tid; i < 512; i += 256) {
        int svi = cls * NV + ((i < NV) ? i : NV - 1);
        sn_sh[i] = svnorm[svi];
    }
    for (int i = tid; i < 64 * R; i += 256) tred[i] = 0.0f;

    float xnr[2][4];
#pragma unroll
    for (int ti = 0; ti < 2; ++ti)
#pragma unroll
        for (int reg = 0; reg < 4; ++reg)
            xnr[ti][reg] = xnorm[n0 + wm * 32 + ti * 16 + quad * 4 + reg];

    float tloc[8][R];
#pragma unroll
    for (int i = 0; i < 8; ++i)
#pragma unroll
        for (int r = 0; r < R; ++r) tloc[i][r] = 0.0f;

    // frag read offsets (f16 units), phase-invariant, conflict-free
    int aoff[2], boff[4];
#pragma unroll
    for (int ti = 0; ti < 2; ++ti) {
        int row = wm * 32 + ti * 16 + lx;
        aoff[ti] = row * LW + ((quad + (row >> 3)) & 3) * 8;
    }
#pragma unroll
    for (int tj = 0; tj < 4; ++tj) {
        int row = wn * 64 + tj * 16 + lx;
        boff[tj] = row * LW + ((quad + (row >> 3)) & 3) * 8;
    }
    // staging maps: A thread->(row=tid/4, ks=tid%4); B thread->(row=tid/2, 2 slots)
    const int arow = tid >> 2, aks = tid & 3;
    const int adst = arow * LW + ((aks + (arow >> 3)) & 3) * 8;
    const int baseA = (n0 + arow) * D + aks * 8;          // + kb*32
    const int brow = tid >> 1, bks = (tid & 1) * 2;
    const int bdst0 = brow * LW + ((bks     + (brow >> 3)) & 3) * 8;
    const int bdst1 = brow * LW + ((bks + 1 + (brow >> 3)) & 3) * 8;
    const int segend = cls * NV + NV - 1;

    f32x4 accM[2][4], accC[2][4];
#pragma unroll
    for (int ti = 0; ti < 2; ++ti)
#pragma unroll
        for (int tj = 0; tj < 4; ++tj) {
            accM[ti][tj] = (f32x4){0.f, 0.f, 0.f, 0.f};
            accC[ti][tj] = (f32x4){0.f, 0.f, 0.f, 0.f};
        }

    f16x8 pAh, pAl, pBh0, pBh1, pBl0, pBl1;
    auto loadG = [&](int ch, int kb) {
        int offA = baseA + kb * 32;
        pAh = *(const f16x8*)(xh + offA);
        pAl = *(const f16x8*)(xl + offA);
        int svr = cls * NV + ch * 128 + brow;
        if (svr > segend) svr = segend;
        int offB = svr * D + bks * 8 + kb * 32;
        pBh0 = *(const f16x8*)(sh + offB);
        pBh1 = *(const f16x8*)(sh + offB + 8);
        pBl0 = *(const f16x8*)(sl + offB);
        pBl1 = *(const f16x8*)(sl + offB + 8);
    };

    loadG(0, 0);
    __syncthreads();

    for (int ph = 0; ph < 32; ++ph) {
        const int ch = ph >> 3, kb = ph & 7;
        // write prefetched tile (single buffer; prior phase's reads done)
        *(f16x8*)(&As[0][adst])  = pAh;
        *(f16x8*)(&As[1][adst])  = pAl;
        *(f16x8*)(&Bs[0][bdst0]) = pBh0;
        *(f16x8*)(&Bs[0][bdst1]) = pBh1;
        *(f16x8*)(&Bs[1][bdst0]) = pBl0;
        *(f16x8*)(&Bs[1][bdst1]) = pBl1;
        __syncthreads();

        if (ph < 31) loadG((ph + 1) >> 3, (ph + 1) & 7);  // in flight under MFMAs

        f16x8 Ah[2], Al[2];
#pragma unroll
        for (int ti = 0; ti < 2; ++ti) {
            Ah[ti] = *(const f16x8*)(&As[0][aoff[ti]]);
            Al[ti] = *(const f16x8*)(&As[1][aoff[ti]]);
        }
#pragma unroll
        for (int tj = 0; tj < 4; ++tj) {
            f16x8 Bh = *(const f16x8*)(&Bs[0][boff[tj]]);
            f16x8 Bl = *(const f16x8*)(&Bs[1][boff[tj]]);
#pragma unroll
            for (int ti = 0; ti < 2; ++ti) {
                accM[ti][tj] = __builtin_amdgcn_mfma_f32_16x16x32_f16(
                    Ah[ti], Bh, accM[ti][tj], 0, 0, 0);
                accC[ti][tj] = __builtin_amdgcn_mfma_f32_16x16x32_f16(
                    Ah[ti], Bl, accC[ti][tj], 0, 0, 0);
                accC[ti][tj] = __builtin_amdgcn_mfma_f32_16x16x32_f16(
                    Al[ti], Bh, accC[ti][tj], 0, 0, 0);
            }
        }
        __syncthreads();

        if (kb == 7) {                      // chunk epilogue (VALU)
#pragma unroll
            for (int tj = 0; tj < 4; ++tj) {
                int cseg = ch * 128 + wn * 64 + tj * 16 + lx;
                float sn = sn_sh[cseg];
                float av[R];
#pragma unroll
                for (int r = 0; r < R; ++r) av[r] = a_sh[r][cseg];
#pragma unroll
                for (int ti = 0; ti < 2; ++ti)
#pragma unroll
                    for (int reg = 0; reg < 4; ++reg) {
                        float dot = accM[ti][tj][reg]
                                  + accC[ti][tj][reg] * (1.0f / 4096.0f);
                        float e  = fmaf(2.0f * GAMMA, dot,
                                        -GAMMA * (xnr[ti][reg] + sn));
                        float kv = __expf(e);
#pragma unroll
                        for (int r = 0; r < R; ++r)
                            tloc[ti * 4 + reg][r] =
                                fmaf(av[r], kv, tloc[ti * 4 + reg][r]);
                    }
            }
#pragma unroll
            for (int ti = 0; ti < 2; ++ti)
#pragma unroll
                for (int tj = 0; tj < 4; ++tj) {
                    accM[ti][tj] = (f32x4){0.f, 0.f, 0.f, 0.f};
                    accC[ti][tj] = (f32x4){0.f, 0.f, 0.f, 0.f};
                }
        }
    }

    // butterfly-sum the 16 lanes sharing each row, then atomics from lx==0
#pragma unroll
    for (int i = 0; i < 8; ++i)
#pragma unroll
        for (int r = 0; r < R; ++r) {
            float v = tloc[i][r];
            v += __shfl_xor(v, 1, 64);
            v += __shfl_xor(v, 2, 64);
            v += __shfl_xor(v, 4, 64);
            v += __shfl_xor(v, 8, 64);
            tloc[i][r] = v;
        }
    if (lx == 0) {
#pragma unroll
        for (int i = 0; i < 8; ++i) {
            int ti = i >> 2, reg = i & 3;
            int row = wm * 32 + ti * 16 + quad * 4 + reg;
#pragma unroll
            for (int r = 0; r < R; ++r)
                atomicAdd(&tred[row * R + r], tloc[i][r]);
        }
    }
    __syncthreads();
    for (int i = tid; i < 64 * R; i += 256) {
        int row = i / R, r = i - row * R;
        T[(size_t)(n0 + row) * 90 + r * 10 + cls] = tred[i];
    }
}

// ---------------- pairwise voting + argmax ----------------------------------
__global__ __launch_bounds__(256) void vote_kernel(const float* __restrict__ T,
                                                   const float* __restrict__ b,
                                                   int* __restrict__ out) {
    int n = blockIdx.x * blockDim.x + threadIdx.x;
    if (n >= N) return;
    const float* Tn = T + (size_t)n * 90;
    float tv[90];
#pragma unroll
    for (int i = 0; i < 90; ++i) tv[i] = Tn[i];
    int counts[C];
#pragma unroll
    for (int k = 0; k < C; ++k) counts[k] = 0;
    int p = 0;
#pragma unroll
    for (int i = 0; i < C; ++i) {
#pragma unroll
        for (int j = i + 1; j < C; ++j) {
            float c = tv[i * 10 + j] + tv[(j - 1) * 10 + i] + b[p];
            if (c > 0.f) counts[i]++; else counts[j]++;
            ++p;
        }
    }
    int best = 0;
#pragma unroll
    for (int k = 1; k < C; ++k)
        if (counts[k] > counts[best]) best = k;
    out[n]     = best;
    out[N + n] = best;
}

extern "C" void kernel_launch(void* const* d_in, const int* in_sizes, int n_in,
                              void* d_out, int out_size, void* d_ws, size_t ws_size,
                              hipStream_t stream) {
    const float* x  = (const float*)d_in[0];   // [8192,256]
    const float* sv = (const float*)d_in[1];   // [5000,256]
    const float* a  = (const float*)d_in[2];   // [9,5000]
    const float* b  = (const float*)d_in[3];   // [45]
    int* out = (int*)d_out;

    char* wp = (char*)d_ws;
    _Float16* xh = (_Float16*)wp;  wp += (size_t)N * D * 2;
    _Float16* xl = (_Float16*)wp;  wp += (size_t)N * D * 2;
    _Float16* sh = (_Float16*)wp;  wp += (size_t)S * D * 2;
    _Float16* sl = (_Float16*)wp;  wp += (size_t)S * D * 2;
    float* xnorm  = (float*)wp;    wp += (size_t)N * 4;
    float* svnorm = (float*)wp;    wp += (size_t)S * 4;
    float* T      = (float*)wp;

    {   // fused split + norms
        int waves = N + S;
        prep_kernel<<<(waves * 64 + 255) / 256, 256, 0, stream>>>(
            x, sv, xh, xl, sh, sl, xnorm, svnorm);
    }
    {   // GEMM
        dim3 grid(N / 64, C);
        svc_gemm<<<grid, 256, 0, stream>>>(xh, xl, sh, sl, a, xnorm, svnorm, T);
    }
    {   // voting
        vote_kernel<<<N / 256, 256, 0, stream>>>(T, b, out);
    }
}